// Round 8
// baseline (356.021 us; speedup 1.0000x reference)
//
#include <hip/hip_runtime.h>

// LinearConv2D: y[b, o=g*8+n, fi, t] =
//   sum_{d<8, fr<2, w<16} x[b, g*8+d, 2*fi+fr, 4*t+w] * wt[g*8+n, d, 2*fi+fr, w]
// Shapes: x[16,64,128,256] f32, wt[64,8,128,16] f32, out[16,64,64,61] f32.
//
// R8: WEIGHT-STATIONARY redesign. Every prior variant re-loaded weights
// in-loop (scalar s_load: serialized lgkmcnt drains; LDS: data-path bound)
// and burned ~3x FMA-count in repack/addr VALU. New mapping:
//   wave = one (b,g,fi); lane = (n,d) = (lane>>3, lane&7).
// Each lane holds its 32 weights (2fr x 16w) in VGPRs, loaded ONCE.
// Loop over t in groups of 4: load shared x window (7 float4 per fr; the
// 8 n-lanes sharing d hit the same lines -> HW merges), 32 FMA per t,
// 3-step ds_swizzle butterfly over d (xor 1,2,4), lane d==0 stores.
// In-loop VALU ~= 1.3x FMA. Floor: 8192 waves x 61t x ~42inst x 2cy /
// 1024 SIMDs ~= 18us. Named float4 vars only (no arrays -> no scratch).

namespace {
constexpr int kC  = 64;
constexpr int kF  = 128;
constexpr int kT  = 256;
constexpr int kG  = 8;
constexpr int kD  = 8;
constexpr int kN  = 8;
constexpr int kW  = 16;
constexpr int kNT = 61;   // (256-16)/4 + 1
constexpr int kO  = 64;
constexpr int kFP = 64;   // (128-2)/2 + 1
}

__device__ __forceinline__ float dot4(const float4& a, const float4& b, float acc) {
  acc = fmaf(a.x, b.x, acc);
  acc = fmaf(a.y, b.y, acc);
  acc = fmaf(a.z, b.z, acc);
  acc = fmaf(a.w, b.w, acc);
  return acc;
}

// Butterfly sum over the d bits (lane bits 0..2). BitMode swizzle:
// offset = (xor<<10) | 0x1F  -> lane' = lane ^ xor (within 32-lane groups).
__device__ __forceinline__ float dsum8(float v) {
  v += __int_as_float(__builtin_amdgcn_ds_swizzle(__float_as_int(v), 0x041F));
  v += __int_as_float(__builtin_amdgcn_ds_swizzle(__float_as_int(v), 0x081F));
  v += __int_as_float(__builtin_amdgcn_ds_swizzle(__float_as_int(v), 0x101F));
  return v;
}

__global__ __launch_bounds__(256, 4)
void lc2d_kernel(const float* __restrict__ x,
                 const float* __restrict__ wt,
                 float* __restrict__ out) {
  const int tid  = threadIdx.x;
  const int lane = tid & 63;
  const int wv   = tid >> 6;            // wave -> fi sub-index
  const int n    = lane >> 3;           // 0..7
  const int d    = lane & 7;            // 0..7
  const int fi   = blockIdx.x * 4 + wv; // 0..63
  const int g    = blockIdx.y;          // 0..7
  const int b    = blockIdx.z;          // 0..15

  // ---- Load this lane's 32 weights ONCE (stay in VGPRs). ----
  // wt[o=g*8+n][d][f=2*fi+fr][w]; per-(o,d) block is 2048 floats, f row = 16.
  const float* wsrc = wt + (((size_t)(g * kN + n) * kD + d) * kF + fi * 2) * kW;
  const float4 wa0 = ((const float4*)wsrc)[0];   // fr=0, w 0..3
  const float4 wa1 = ((const float4*)wsrc)[1];
  const float4 wa2 = ((const float4*)wsrc)[2];
  const float4 wa3 = ((const float4*)wsrc)[3];
  const float4 wb0 = ((const float4*)wsrc)[4];   // fr=1, w 0..3
  const float4 wb1 = ((const float4*)wsrc)[5];
  const float4 wb2 = ((const float4*)wsrc)[6];
  const float4 wb3 = ((const float4*)wsrc)[7];

  // x rows for this lane's d: fr=0 and fr=1.
  const float* xr0 = x + (((size_t)b * kC + g * kD + d) * kF + fi * 2) * kT;
  const float* xr1 = xr0 + kT;

  // Output row base for this lane's n (only d==0 lanes store).
  float* ob = out + ((size_t)b * kO + g * kN + n) * (kFP * kNT) + (size_t)fi * kNT;

#define LC2D_STEP(J, Q0, Q1, Q2, Q3, U0, U1, U2, U3)          \
  {                                                            \
    float s = 0.f;                                             \
    s = dot4(Q0, wa0, s);                                      \
    s = dot4(Q1, wa1, s);                                      \
    s = dot4(Q2, wa2, s);                                      \
    s = dot4(Q3, wa3, s);                                      \
    s = dot4(U0, wb0, s);                                      \
    s = dot4(U1, wb1, s);                                      \
    s = dot4(U2, wb2, s);                                      \
    s = dot4(U3, wb3, s);                                      \
    s = dsum8(s);                                              \
    if (d == 0) ob[4 * k + (J)] = s;                           \
  }

  // 61 = 15 groups of 4 + tail. Group k covers t = 4k..4k+3,
  // window floats [16k, 16k+28) per fr -> 7 float4 each.
  for (int k = 0; k < 15; ++k) {
    const float* p0 = xr0 + 16 * k;
    const float* p1 = xr1 + 16 * k;
    const float4 q0 = ((const float4*)p0)[0];
    const float4 q1 = ((const float4*)p0)[1];
    const float4 q2 = ((const float4*)p0)[2];
    const float4 q3 = ((const float4*)p0)[3];
    const float4 q4 = ((const float4*)p0)[4];
    const float4 q5 = ((const float4*)p0)[5];
    const float4 q6 = ((const float4*)p0)[6];
    const float4 u0 = ((const float4*)p1)[0];
    const float4 u1 = ((const float4*)p1)[1];
    const float4 u2 = ((const float4*)p1)[2];
    const float4 u3 = ((const float4*)p1)[3];
    const float4 u4 = ((const float4*)p1)[4];
    const float4 u5 = ((const float4*)p1)[5];
    const float4 u6 = ((const float4*)p1)[6];

    LC2D_STEP(0, q0, q1, q2, q3, u0, u1, u2, u3)
    LC2D_STEP(1, q1, q2, q3, q4, u1, u2, u3, u4)
    LC2D_STEP(2, q2, q3, q4, q5, u2, u3, u4, u5)
    LC2D_STEP(3, q3, q4, q5, q6, u3, u4, u5, u6)
  }
#undef LC2D_STEP

  // Tail: t = 60, window floats [240, 256).
  {
    const float* p0 = xr0 + 240;
    const float* p1 = xr1 + 240;
    const float4 q0 = ((const float4*)p0)[0];
    const float4 q1 = ((const float4*)p0)[1];
    const float4 q2 = ((const float4*)p0)[2];
    const float4 q3 = ((const float4*)p0)[3];
    const float4 u0 = ((const float4*)p1)[0];
    const float4 u1 = ((const float4*)p1)[1];
    const float4 u2 = ((const float4*)p1)[2];
    const float4 u3 = ((const float4*)p1)[3];
    float s = 0.f;
    s = dot4(q0, wa0, s);
    s = dot4(q1, wa1, s);
    s = dot4(q2, wa2, s);
    s = dot4(q3, wa3, s);
    s = dot4(u0, wb0, s);
    s = dot4(u1, wb1, s);
    s = dot4(u2, wb2, s);
    s = dot4(u3, wb3, s);
    s = dsum8(s);
    if (d == 0) ob[60] = s;
  }
}

extern "C" void kernel_launch(void* const* d_in, const int* in_sizes, int n_in,
                              void* d_out, int out_size, void* d_ws, size_t ws_size,
                              hipStream_t stream) {
  const float* x  = (const float*)d_in[0];
  const float* wt = (const float*)d_in[1];
  float* out      = (float*)d_out;

  dim3 grid(16, kG, 16);   // fi/4 x g x b = 2048 blocks of 256 threads
  lc2d_kernel<<<grid, 256, 0, stream>>>(x, wt, out);
}